// Round 1
// baseline (476.596 us; speedup 1.0000x reference)
//
#include <hip/hip_runtime.h>
#include <cmath>

#define BBATCH 8
#define NN 128
#define DD 128      // IN_DIM
#define CC 64       // IN_DIM_E
#define HH 8
#define KK 64
#define HK 512
#define ROWS (BBATCH*NN)     // 1024
#define MATSZ (ROWS*HK)      // 524288 floats per projection matrix

// ---------------- Kernel 1: projections h @ {Wq,Wk,Wv,Wq2,Wk2} ----------------
// grid (16, 40): x = 64-row tile, y = matrix(5) * colTile(8)
__global__ __launch_bounds__(256) void proj_kernel(
    const float* __restrict__ h,
    const float* __restrict__ Wq, const float* __restrict__ Wk,
    const float* __restrict__ Wv, const float* __restrict__ Wq2,
    const float* __restrict__ Wk2, float* __restrict__ ws)
{
    __shared__ float As[64*132];   // 64 rows x 128 k, padded stride 132
    __shared__ float Bs[128*64];   // 128 k x 64 cols
    const int t  = threadIdx.x;
    const int bx = blockIdx.x;
    const int by = blockIdx.y;
    const int m    = by >> 3;
    const int col0 = (by & 7) * 64;
    const float* W = (m==0)?Wq:(m==1)?Wk:(m==2)?Wv:(m==3)?Wq2:Wk2;
    const float scale = (m==1 || m==4) ? 0.125f : 1.0f;   // K^-0.5 on Kh, K2
    float* outp = ws + (size_t)m * MATSZ;
    const int row0 = bx * 64;

    // A tile: 64x128 (h rows)
    for (int r = 0; r < 8; ++r) {
        int idx = t + 256*r;          // float4 index among 2048
        int row = idx >> 5;
        int c4  = idx & 31;
        float4 v = ((const float4*)(h + (size_t)(row0+row)*DD))[c4];
        float* dst = As + row*132 + c4*4;
        dst[0]=v.x; dst[1]=v.y; dst[2]=v.z; dst[3]=v.w;
    }
    // B tile: 128x64 (W rows)
    for (int r = 0; r < 8; ++r) {
        int idx = t + 256*r;
        int kk = idx >> 4;
        int c4 = idx & 15;
        ((float4*)Bs)[idx] = ((const float4*)(W + (size_t)kk*HK + col0))[c4];
    }
    __syncthreads();

    const int tx = t & 15, ty = t >> 4;
    float acc[4][4] = {};
    for (int kk = 0; kk < 128; ++kk) {
        float4 bv = ((float4*)Bs)[kk*16 + tx];
        #pragma unroll
        for (int ii = 0; ii < 4; ++ii) {
            float av = As[(ty*4+ii)*132 + kk];
            acc[ii][0] += av*bv.x; acc[ii][1] += av*bv.y;
            acc[ii][2] += av*bv.z; acc[ii][3] += av*bv.w;
        }
    }
    #pragma unroll
    for (int ii = 0; ii < 4; ++ii) {
        int r = row0 + ty*4 + ii;
        float4 v = make_float4(acc[ii][0]*scale, acc[ii][1]*scale,
                               acc[ii][2]*scale, acc[ii][3]*scale);
        ((float4*)(outp + (size_t)r*HK + col0))[tx] = v;
    }
}

// ---------------- Kernel 2: fused edge-GEMM + scores + softmax-ish + V ----------------
// one block per (b,i); 256 threads = 4 waves
__global__ __launch_bounds__(256, 2) void attn_kernel(
    const float* __restrict__ e, const float* __restrict__ k_RW,
    const float* __restrict__ mask, const int* __restrict__ adj,
    const float* __restrict__ We, const float* __restrict__ We2,
    const float* __restrict__ ws, float* __restrict__ out)
{
    __shared__ float e_s[NN*CC];       // 32 KB, e[b,i,j,c]
    __shared__ float w12_s[2*CC*KK];   // 32 KB, per-head We/We2 64x64 blocks
    __shared__ float q_s[2*HK];        // Qh row | Q2 row
    __shared__ float sc_s[HH*NN];      // scores then weights
    __shared__ float kwm_s[NN];        // k_RW * mask_j
    __shared__ int   jp1_s[NN];
    __shared__ int   jp0_s[NN];
    __shared__ int   cnts[2];

    const int t    = threadIdx.x;
    const int blk  = blockIdx.x;       // b*128 + i
    const int b    = blk >> 7;
    const int i    = blk & 127;
    const int lane = t & 63;
    const int w    = t >> 6;

    const float* Qh = ws;
    const float* Kh = ws + (size_t)MATSZ;
    const float* Vh = ws + 2*(size_t)MATSZ;
    const float* Q2 = ws + 3*(size_t)MATSZ;
    const float* K2 = ws + 4*(size_t)MATSZ;

    if (t == 0) { cnts[0] = 0; cnts[1] = 0; }
    __syncthreads();

    // stage e[b,i,:,:] (8192 floats), Q rows, adj/k_RW/mask, and adj-sorted j lists
    const float* eptr = e + (size_t)blk * (NN*CC);
    for (int r = 0; r < 8; ++r)
        ((float4*)e_s)[t + 256*r] = ((const float4*)eptr)[t + 256*r];
    if (t < 128) ((float4*)q_s)[t] = ((const float4*)(Qh + (size_t)blk*HK))[t];
    else         ((float4*)q_s)[t] = ((const float4*)(Q2 + (size_t)blk*HK))[t-128];
    const float maski = mask[b*NN + i];
    if (t < 128) {
        int a = adj[blk*NN + t];
        kwm_s[t] = k_RW[(size_t)blk*NN + t] * mask[b*NN + t];
        if (a) { int s1 = atomicAdd(&cnts[1], 1); jp1_s[s1] = t; }
        else   { int s0 = atomicAdd(&cnts[0], 1); jp0_s[s0] = t; }
    }
    __syncthreads();
    const int n1 = cnts[1];

    const float* KhB = Kh + (size_t)b*NN*HK;
    const float* K2B = K2 + (size_t)b*NN*HK;

    for (int hh = 0; hh < HH; ++hh) {
        __syncthreads();   // previous iter's W readers done
        // stage We[:, hh*64:+64] and We2 same -> LDS [c][k]
        for (int r = 0; r < 4; ++r) {
            int idx = t + 256*r;      // 1024 float4 per matrix
            int c  = idx >> 4;
            int k4 = idx & 15;
            ((float4*)w12_s)[idx]        = ((const float4*)(We  + (size_t)c*HK + hh*KK))[k4];
            ((float4*)(w12_s+CC*KK))[idx]= ((const float4*)(We2 + (size_t)c*HK + hh*KK))[k4];
        }
        __syncthreads();

        // each wave handles 8 quads of 4 permuted j's; lane = k
        for (int qq = 0; qq < 8; ++qq) {
            const int qi = w*8 + qq;
            const int p0 = qi*4;
            int js[4]; bool as[4];
            #pragma unroll
            for (int q = 0; q < 4; ++q) {
                int p = p0 + q;
                as[q] = (p < n1);
                js[q] = as[q] ? jp1_s[p] : jp0_s[p - n1];
            }
            float Ev[4] = {0.f, 0.f, 0.f, 0.f};
            if (as[0] == as[3]) {      // sorted => quad uniform
                const float* wp = w12_s + (as[0] ? 0 : CC*KK);
                #pragma unroll 4
                for (int c4 = 0; c4 < 16; ++c4) {
                    float ea0[4], ea1[4], ea2[4], ea3[4];
                    *(float4*)ea0 = ((float4*)e_s)[js[0]*16 + c4];
                    *(float4*)ea1 = ((float4*)e_s)[js[1]*16 + c4];
                    *(float4*)ea2 = ((float4*)e_s)[js[2]*16 + c4];
                    *(float4*)ea3 = ((float4*)e_s)[js[3]*16 + c4];
                    #pragma unroll
                    for (int q = 0; q < 4; ++q) {
                        float wv = wp[(c4*4+q)*KK + lane];
                        Ev[0] += ea0[q]*wv; Ev[1] += ea1[q]*wv;
                        Ev[2] += ea2[q]*wv; Ev[3] += ea3[q]*wv;
                    }
                }
            } else {                   // the single straddling quad: per-j select
                #pragma unroll
                for (int q = 0; q < 4; ++q) {
                    const float* wp = w12_s + (as[q] ? 0 : CC*KK);
                    float a2 = 0.f;
                    for (int c4 = 0; c4 < 16; ++c4) {
                        float ea[4];
                        *(float4*)ea = ((float4*)e_s)[js[q]*16 + c4];
                        #pragma unroll
                        for (int q2 = 0; q2 < 4; ++q2)
                            a2 += ea[q2] * wp[(c4*4+q2)*KK + lane];
                    }
                    Ev[q] = a2;
                }
            }
            // triple product + wave reduction
            float pr[4];
            #pragma unroll
            for (int q = 0; q < 4; ++q) {
                float qv = q_s[(as[q] ? 0 : HK) + hh*KK + lane];
                float kv = (as[q] ? KhB : K2B)[(size_t)js[q]*HK + hh*KK + lane];
                pr[q] = Ev[q] * qv * kv;
            }
            #pragma unroll
            for (int mm = 32; mm >= 1; mm >>= 1) {
                pr[0] += __shfl_xor(pr[0], mm);
                pr[1] += __shfl_xor(pr[1], mm);
                pr[2] += __shfl_xor(pr[2], mm);
                pr[3] += __shfl_xor(pr[3], mm);
            }
            if (lane == 0) {
                sc_s[hh*NN + js[0]] = pr[0]; sc_s[hh*NN + js[1]] = pr[1];
                sc_s[hh*NN + js[2]] = pr[2]; sc_s[hh*NN + js[3]] = pr[3];
            }
        }
    }
    __syncthreads();

    // weights: exp(s) * mask_i * mask_j * k_RW   (global max cancels in the ratio)
    #pragma unroll
    for (int r = 0; r < 4; ++r) {
        int idx = t + 256*r;
        int j = idx & 127;
        sc_s[idx] = expf(sc_s[idx]) * kwm_s[j] * maski;
    }
    __syncthreads();

    // per-head denom + weighted V sum; wave w handles heads w and w+4
    const float* VB = Vh + (size_t)b*NN*HK;
    for (int hp = 0; hp < 2; ++hp) {
        const int hh = w + hp*4;
        float d = sc_s[hh*NN + lane] + sc_s[hh*NN + 64 + lane];
        #pragma unroll
        for (int mm = 32; mm >= 1; mm >>= 1) d += __shfl_xor(d, mm);
        float acc = 0.f;
        const float* vb = VB + hh*KK + lane;
        #pragma unroll 4
        for (int j4 = 0; j4 < 32; ++j4) {
            float wa[4];
            *(float4*)wa = ((float4*)sc_s)[hh*32 + j4];
            acc += wa[0] * vb[(size_t)(j4*4+0)*HK];
            acc += wa[1] * vb[(size_t)(j4*4+1)*HK];
            acc += wa[2] * vb[(size_t)(j4*4+2)*HK];
            acc += wa[3] * vb[(size_t)(j4*4+3)*HK];
        }
        out[(size_t)blk*HK + hh*KK + lane] = acc / fmaxf(d, 1e-6f);
    }
}

extern "C" void kernel_launch(void* const* d_in, const int* in_sizes, int n_in,
                              void* d_out, int out_size, void* d_ws, size_t ws_size,
                              hipStream_t stream) {
    const float* h    = (const float*)d_in[0];
    const float* e    = (const float*)d_in[1];
    const float* kRW  = (const float*)d_in[2];
    const float* mask = (const float*)d_in[3];
    const int*   adj  = (const int*)d_in[4];
    const float* Wq   = (const float*)d_in[5];
    const float* Wk   = (const float*)d_in[6];
    const float* Wv   = (const float*)d_in[7];
    const float* We   = (const float*)d_in[8];
    const float* Wq2  = (const float*)d_in[9];
    const float* Wk2  = (const float*)d_in[10];
    const float* We2  = (const float*)d_in[11];
    float* out = (float*)d_out;
    float* ws  = (float*)d_ws;   // needs 5*524288 floats = 10.5 MB

    proj_kernel<<<dim3(16, 40), 256, 0, stream>>>(h, Wq, Wk, Wv, Wq2, Wk2, ws);
    attn_kernel<<<dim3(1024), 256, 0, stream>>>(e, kRW, mask, adj, We, We2, ws, out);
}

// Round 2
// 181.478 us; speedup vs baseline: 2.6262x; 2.6262x over previous
//
#include <hip/hip_runtime.h>
#include <cmath>

#define BBATCH 8
#define NN 128
#define DD 128      // IN_DIM
#define CC 64       // IN_DIM_E
#define HH 8
#define KK 64
#define HK 512
#define ROWS (BBATCH*NN)     // 1024
#define MATSZ (ROWS*HK)      // 524288 elements per projection matrix

typedef __attribute__((ext_vector_type(8))) short sh8;    // 8 bf16 = 4 VGPRs
typedef __attribute__((ext_vector_type(4))) float f32x4;  // MFMA C/D

static __device__ __forceinline__ unsigned short f2bf(float f) {
    union { float f; unsigned u; } v; v.f = f;
    unsigned r = v.u + 0x7fffu + ((v.u >> 16) & 1u);   // RNE
    return (unsigned short)(r >> 16);
}
static __device__ __forceinline__ float bf2f(unsigned short u) {
    union { unsigned u; float f; } v; v.u = ((unsigned)u) << 16;
    return v.f;
}

// ws layout:
//   [0 .. MATSZ)          Qh   fp32  [b*n][hk]
//   [MATSZ .. 2M)         Q2   fp32
//   [2M .. 3M)            Vh   fp32
//   (ushort*)(ws+3M):     K1bf bf16  [b*n][hk]   (pre-scaled by K^-0.5)
//   +MATSZ ushorts:       K2bf bf16
//   +2*MATSZ ushorts:     Wfrag bf16 [2][8 heads][8 frags][64 lanes][8]  (A-operand order)

// ---------------- Kernel 1: projections + W fragment conversion ----------------
// grid (16, 42): by<40: proj tile (x = 64-row tile, by = matrix(5)*colTile(8));
//                by=40/41: convert We/We2 to A-fragment-order bf16
__global__ __launch_bounds__(256) void proj_kernel(
    const float* __restrict__ h,
    const float* __restrict__ Wq, const float* __restrict__ Wk,
    const float* __restrict__ Wv, const float* __restrict__ Wq2,
    const float* __restrict__ Wk2,
    const float* __restrict__ We, const float* __restrict__ We2,
    float* __restrict__ ws)
{
    const int t  = threadIdx.x;
    const int bx = blockIdx.x;
    const int by = blockIdx.y;

    if (by >= 40) {
        // ---- W -> A-fragment-order bf16 ----
        // A-frag for E^T GEMM: A[m=k_out][kc=c]; lane = g4*16 + (k&15), reg jj = c&7
        const int v = by - 40;
        const float* W = v ? We2 : We;
        unsigned short* Wfrag = (unsigned short*)(ws + 3*(size_t)MATSZ) + 2*(size_t)MATSZ
                              + (size_t)v * 32768;
        const int g   = bx * 256 + t;     // 0..4095
        const int c   = g >> 6;           // 0..63
        const int sub = g & 63;
        const int hh  = sub >> 3;         // head
        const int k0  = (sub & 7) * 8;    // k within head, 8-aligned
        float4 w0 = *(const float4*)(W + (size_t)c*HK + hh*KK + k0);
        float4 w1 = *(const float4*)(W + (size_t)c*HK + hh*KK + k0 + 4);
        float wv[8] = {w0.x,w0.y,w0.z,w0.w,w1.x,w1.y,w1.z,w1.w};
        const int cb = c >> 5, g4 = (c >> 3) & 3, jj = c & 7;
        #pragma unroll
        for (int q = 0; q < 8; ++q) {
            int k  = k0 + q;
            int mb = k >> 4, m = k & 15;
            Wfrag[(size_t)hh*4096 + (mb*2+cb)*512 + (g4*16+m)*8 + jj] = f2bf(wv[q]);
        }
        return;
    }

    __shared__ float As[64*132];
    __shared__ float Bs[128*64];
    const int m    = by >> 3;
    const int col0 = (by & 7) * 64;
    const float* W = (m==0)?Wq:(m==1)?Wk:(m==2)?Wv:(m==3)?Wq2:Wk2;
    const float scale = (m==1 || m==4) ? 0.125f : 1.0f;
    const int row0 = bx * 64;

    for (int r = 0; r < 8; ++r) {
        int idx = t + 256*r;
        int row = idx >> 5;
        int c4  = idx & 31;
        float4 v = ((const float4*)(h + (size_t)(row0+row)*DD))[c4];
        float* dst = As + row*132 + c4*4;
        dst[0]=v.x; dst[1]=v.y; dst[2]=v.z; dst[3]=v.w;
    }
    for (int r = 0; r < 8; ++r) {
        int idx = t + 256*r;
        int kk = idx >> 4;
        int c4 = idx & 15;
        ((float4*)Bs)[idx] = ((const float4*)(W + (size_t)kk*HK + col0))[c4];
    }
    __syncthreads();

    const int tx = t & 15, ty = t >> 4;
    float acc[4][4] = {};
    for (int kk = 0; kk < 128; ++kk) {
        float4 bv = ((float4*)Bs)[kk*16 + tx];
        #pragma unroll
        for (int ii = 0; ii < 4; ++ii) {
            float av = As[(ty*4+ii)*132 + kk];
            acc[ii][0] += av*bv.x; acc[ii][1] += av*bv.y;
            acc[ii][2] += av*bv.z; acc[ii][3] += av*bv.w;
        }
    }

    if (m == 1 || m == 4) {
        unsigned short* kout = (unsigned short*)(ws + 3*(size_t)MATSZ)
                             + (m==4 ? (size_t)MATSZ : 0);
        #pragma unroll
        for (int ii = 0; ii < 4; ++ii) {
            int r = row0 + ty*4 + ii;
            ushort4 u;
            u.x = f2bf(acc[ii][0]*scale); u.y = f2bf(acc[ii][1]*scale);
            u.z = f2bf(acc[ii][2]*scale); u.w = f2bf(acc[ii][3]*scale);
            *(ushort4*)(kout + (size_t)r*HK + col0 + tx*4) = u;
        }
    } else {
        float* outp = ws + (m==0 ? 0 : (m==3 ? (size_t)MATSZ : 2*(size_t)MATSZ));
        #pragma unroll
        for (int ii = 0; ii < 4; ++ii) {
            int r = row0 + ty*4 + ii;
            float4 v = make_float4(acc[ii][0], acc[ii][1], acc[ii][2], acc[ii][3]);
            ((float4*)(outp + (size_t)r*HK + col0))[tx] = v;
        }
    }
}

// ---------------- Kernel 2: MFMA edge-GEMM + scores + weights + V ----------------
// one block per (b,i); 4 waves; wave w handles units (v,h) = w*4+uu
__global__ __launch_bounds__(256, 2) void attn_kernel(
    const float* __restrict__ e, const float* __restrict__ k_RW,
    const float* __restrict__ mask, const int* __restrict__ adj,
    const float* __restrict__ ws, float* __restrict__ out)
{
    __shared__ sh8   ef8[1024];        // 16KB: e as bf16 B-frags [8 jb][2 cb][64 lanes][8]
    __shared__ float sc_s[2*HH*NN];    // 8KB: [v][h][j] scores, then weights in v=0 half
    __shared__ float kwm_s[NN];
    __shared__ int   ad_s[NN];

    const int t    = threadIdx.x;
    const int blk  = blockIdx.x;
    const int b    = blk >> 7;
    const int i    = blk & 127;
    const int lane = t & 63;
    const int w    = t >> 6;

    const float* Vh   = ws + 2*(size_t)MATSZ;
    const unsigned short* Kbf   = (const unsigned short*)(ws + 3*(size_t)MATSZ);
    const unsigned short* Wfrag = Kbf + 2*(size_t)MATSZ;
    unsigned short* ef = (unsigned short*)ef8;

    // ---- phase 0: stage e -> bf16 B-fragments; kwm/adj -> LDS ----
    // B-frag element (j,c): frag f=(j>>4)*2+(c>>5), lane=((c>>3)&3)*16+(j&15), reg=c&7
    const float* eptr = e + (size_t)blk * (NN*CC);
    #pragma unroll
    for (int r = 0; r < 8; ++r) {
        int idx = t + 256*r;          // float4 index: j = idx>>4, c0 = (idx&15)*4
        int j  = idx >> 4;
        int c0 = (idx & 15) * 4;
        float4 v = ((const float4*)eptr)[idx];
        ushort4 u;
        u.x = f2bf(v.x); u.y = f2bf(v.y); u.z = f2bf(v.z); u.w = f2bf(v.w);
        int f  = (j >> 4)*2 + (c0 >> 5);
        int ln = ((c0 >> 3) & 3)*16 + (j & 15);
        *(ushort4*)(ef + f*512 + ln*8 + (c0 & 7)) = u;
    }
    if (t < NN) {
        kwm_s[t] = k_RW[(size_t)blk*NN + t] * mask[b*NN + t];
        ad_s[t]  = adj[(size_t)blk*NN + t];
    }
    const float maski = mask[b*NN + i];
    __syncthreads();

    // ---- phase 1: per unit (v,h): E^T = W_v^T @ e^T via MFMA, contract k on VALU ----
    const int jl = lane & 15;
    const int kq = (lane >> 4) * 4;    // k sub-offset of this lane's 4 acc rows
    #pragma unroll 1
    for (int uu = 0; uu < 4; ++uu) {
        const int unit = w*4 + uu;
        const int v  = unit >> 3;
        const int hh = unit & 7;
        const unsigned short* wA = Wfrag + (size_t)v*32768 + (size_t)hh*4096;
        sh8 aF[4][2];
        #pragma unroll
        for (int mb = 0; mb < 4; ++mb)
            #pragma unroll
            for (int cb = 0; cb < 2; ++cb)
                aF[mb][cb] = ((const sh8*)wA)[(mb*2+cb)*64 + lane];
        const float* Qrow = ws + (size_t)v*MATSZ + (size_t)blk*HK + hh*KK;
        float4 qv[4];
        #pragma unroll
        for (int mb = 0; mb < 4; ++mb)
            qv[mb] = *(const float4*)(Qrow + mb*16 + kq);
        const unsigned short* Krow = Kbf + (size_t)v*MATSZ + (size_t)b*NN*HK + hh*KK + kq;

        #pragma unroll 1
        for (int nb = 0; nb < 8; ++nb) {
            f32x4 acc[4];
            #pragma unroll
            for (int mb = 0; mb < 4; ++mb) acc[mb] = (f32x4){0.f,0.f,0.f,0.f};
            #pragma unroll
            for (int cb = 0; cb < 2; ++cb) {
                sh8 bF = ((const sh8*)ef)[(nb*2+cb)*64 + lane];
                #pragma unroll
                for (int mb = 0; mb < 4; ++mb)
                    acc[mb] = __builtin_amdgcn_mfma_f32_16x16x32_bf16(
                                  aF[mb][cb], bF, acc[mb], 0, 0, 0);
            }
            const int j = nb*16 + jl;
            const unsigned short* kr = Krow + (size_t)j*HK;
            float p = 0.f;
            #pragma unroll
            for (int mb = 0; mb < 4; ++mb) {
                ushort4 kv = *(const ushort4*)(kr + mb*16);
                float4 q = qv[mb];
                p += acc[mb][0] * (q.x * bf2f(kv.x));
                p += acc[mb][1] * (q.y * bf2f(kv.y));
                p += acc[mb][2] * (q.z * bf2f(kv.z));
                p += acc[mb][3] * (q.w * bf2f(kv.w));
            }
            p += __shfl_xor(p, 16);
            p += __shfl_xor(p, 32);
            if (lane < 16) sc_s[v*(HH*NN) + hh*NN + j] = p;
        }
    }
    __syncthreads();

    // ---- phase 2: select variant per adj, exp, mask, k_RW ----
    #pragma unroll
    for (int r = 0; r < 4; ++r) {
        int idx = t + 256*r;          // h*128 + j
        int j = idx & 127;
        float s = ad_s[j] ? sc_s[idx] : sc_s[HH*NN + idx];
        sc_s[idx] = __expf(s) * kwm_s[j] * maski;
    }
    __syncthreads();

    // ---- phase 3: per-head denom + weighted V sum ----
    const float* VB = Vh + (size_t)b*NN*HK;
    for (int hp = 0; hp < 2; ++hp) {
        const int hh = w + hp*4;
        float d = sc_s[hh*NN + lane] + sc_s[hh*NN + 64 + lane];
        #pragma unroll
        for (int mm = 32; mm >= 1; mm >>= 1) d += __shfl_xor(d, mm);
        float accv = 0.f;
        const float* vb = VB + hh*KK + lane;
        #pragma unroll 4
        for (int j4 = 0; j4 < 32; ++j4) {
            float wa[4];
            *(float4*)wa = ((float4*)sc_s)[hh*32 + j4];
            accv += wa[0] * vb[(size_t)(j4*4+0)*HK];
            accv += wa[1] * vb[(size_t)(j4*4+1)*HK];
            accv += wa[2] * vb[(size_t)(j4*4+2)*HK];
            accv += wa[3] * vb[(size_t)(j4*4+3)*HK];
        }
        out[(size_t)blk*HK + hh*KK + lane] = accv / fmaxf(d, 1e-6f);
    }
}

extern "C" void kernel_launch(void* const* d_in, const int* in_sizes, int n_in,
                              void* d_out, int out_size, void* d_ws, size_t ws_size,
                              hipStream_t stream) {
    const float* h    = (const float*)d_in[0];
    const float* e    = (const float*)d_in[1];
    const float* kRW  = (const float*)d_in[2];
    const float* mask = (const float*)d_in[3];
    const int*   adj  = (const int*)d_in[4];
    const float* Wq   = (const float*)d_in[5];
    const float* Wk   = (const float*)d_in[6];
    const float* Wv   = (const float*)d_in[7];
    const float* We   = (const float*)d_in[8];
    const float* Wq2  = (const float*)d_in[9];
    const float* Wk2  = (const float*)d_in[10];
    const float* We2  = (const float*)d_in[11];
    float* out = (float*)d_out;
    float* ws  = (float*)d_ws;   // 3*2MB fp32 + 2*1MB bf16 + 128KB Wfrag = 8.125MB

    proj_kernel<<<dim3(16, 42), 256, 0, stream>>>(h, Wq, Wk, Wv, Wq2, Wk2, We, We2, ws);
    attn_kernel<<<dim3(1024), 256, 0, stream>>>(e, kRW, mask, adj, ws, out);
}

// Round 4
// 169.215 us; speedup vs baseline: 2.8165x; 1.0725x over previous
//
#include <hip/hip_runtime.h>
#include <cmath>

#define BBATCH 8
#define NN 128
#define DD 128      // IN_DIM
#define CC 64       // IN_DIM_E
#define HH 8
#define KK 64
#define HK 512
#define ROWS (BBATCH*NN)     // 1024
#define MATSZ (ROWS*HK)      // 524288 elements per projection matrix
#define KPAD 72              // K-tile LDS row stride (ushorts): 144B, 16B-aligned, bank-spread

typedef __attribute__((ext_vector_type(8))) short sh8;    // 8 bf16 = 4 VGPRs
typedef __attribute__((ext_vector_type(4))) float f32x4;  // MFMA C/D

static __device__ __forceinline__ unsigned short f2bf(float f) {
    union { float f; unsigned u; } v; v.f = f;
    unsigned r = v.u + 0x7fffu + ((v.u >> 16) & 1u);   // RNE
    return (unsigned short)(r >> 16);
}
static __device__ __forceinline__ float bf2f(unsigned short u) {
    union { unsigned u; float f; } v; v.u = ((unsigned)u) << 16;
    return v.f;
}

// ws layout:
//   f32  [0 .. MATSZ)            Qh
//   f32  [MATSZ .. 2M)           Q2
//   ushort base = (ushort*)(ws + 2M):
//     [0 .. M)                   K1bf (pre-scaled by K^-0.5)
//     [M .. 2M)                  K2bf
//     [2M .. 3M)                 Vbf
//     [3M .. 3M+65536)           Wfrag bf16 [2][8 heads][8 frags][64 lanes][8] (A-op order)

// ---------------- Kernel 1: projections + W fragment conversion ----------------
__global__ __launch_bounds__(256) void proj_kernel(
    const float* __restrict__ h,
    const float* __restrict__ Wq, const float* __restrict__ Wk,
    const float* __restrict__ Wv, const float* __restrict__ Wq2,
    const float* __restrict__ Wk2,
    const float* __restrict__ We, const float* __restrict__ We2,
    float* __restrict__ ws)
{
    const int t  = threadIdx.x;
    const int bx = blockIdx.x;
    const int by = blockIdx.y;

    if (by >= 40) {
        // ---- W -> A-fragment-order bf16 ----
        const int v = by - 40;
        const float* W = v ? We2 : We;
        unsigned short* Wfrag = (unsigned short*)(ws + 2*(size_t)MATSZ) + 3*(size_t)MATSZ
                              + (size_t)v * 32768;
        const int g   = bx * 256 + t;     // 0..4095
        const int c   = g >> 6;           // 0..63
        const int sub = g & 63;
        const int hh  = sub >> 3;
        const int k0  = (sub & 7) * 8;
        float4 w0 = *(const float4*)(W + (size_t)c*HK + hh*KK + k0);
        float4 w1 = *(const float4*)(W + (size_t)c*HK + hh*KK + k0 + 4);
        float wv[8] = {w0.x,w0.y,w0.z,w0.w,w1.x,w1.y,w1.z,w1.w};
        const int cb = c >> 5, g4 = (c >> 3) & 3, jj = c & 7;
        #pragma unroll
        for (int q = 0; q < 8; ++q) {
            int k  = k0 + q;
            int mb = k >> 4, m = k & 15;
            Wfrag[(size_t)hh*4096 + (mb*2+cb)*512 + (g4*16+m)*8 + jj] = f2bf(wv[q]);
        }
        return;
    }

    __shared__ float As[64*136];   // pad 136 -> b128-aligned rows
    __shared__ float Bs[128*64];
    const int m    = by >> 3;
    const int col0 = (by & 7) * 64;
    const float* W = (m==0)?Wq:(m==1)?Wk:(m==2)?Wv:(m==3)?Wq2:Wk2;
    const float scale = (m==1 || m==4) ? 0.125f : 1.0f;
    const int row0 = bx * 64;

    for (int r = 0; r < 8; ++r) {
        int idx = t + 256*r;
        int row = idx >> 5;
        int c4  = idx & 31;
        float4 v = ((const float4*)(h + (size_t)(row0+row)*DD))[c4];
        ((float4*)(As + row*136))[c4] = v;
    }
    for (int r = 0; r < 8; ++r) {
        int idx = t + 256*r;
        int kk = idx >> 4;
        int c4 = idx & 15;
        ((float4*)Bs)[idx] = ((const float4*)(W + (size_t)kk*HK + col0))[c4];
    }
    __syncthreads();

    const int tx = t & 15, ty = t >> 4;
    float acc[4][4] = {};
    #pragma unroll 2
    for (int k4 = 0; k4 < 32; ++k4) {
        float a4[4][4], b4[4][4];
        #pragma unroll
        for (int ii = 0; ii < 4; ++ii)
            *(float4*)a4[ii] = *(const float4*)(As + (ty*4+ii)*136 + k4*4);
        #pragma unroll
        for (int kk = 0; kk < 4; ++kk)
            *(float4*)b4[kk] = ((const float4*)Bs)[(k4*4+kk)*16 + tx];
        #pragma unroll
        for (int ii = 0; ii < 4; ++ii)
            #pragma unroll
            for (int kk = 0; kk < 4; ++kk) {
                acc[ii][0] += a4[ii][kk]*b4[kk][0];
                acc[ii][1] += a4[ii][kk]*b4[kk][1];
                acc[ii][2] += a4[ii][kk]*b4[kk][2];
                acc[ii][3] += a4[ii][kk]*b4[kk][3];
            }
    }

    unsigned short* Ubase = (unsigned short*)(ws + 2*(size_t)MATSZ);
    if (m == 1 || m == 4 || m == 2) {
        unsigned short* outp = Ubase + (m==1 ? 0 : (m==4 ? (size_t)MATSZ : 2*(size_t)MATSZ));
        #pragma unroll
        for (int ii = 0; ii < 4; ++ii) {
            int r = row0 + ty*4 + ii;
            ushort4 u;
            u.x = f2bf(acc[ii][0]*scale); u.y = f2bf(acc[ii][1]*scale);
            u.z = f2bf(acc[ii][2]*scale); u.w = f2bf(acc[ii][3]*scale);
            *(ushort4*)(outp + (size_t)r*HK + col0 + tx*4) = u;
        }
    } else {
        float* outp = ws + (m==0 ? 0 : (size_t)MATSZ);
        #pragma unroll
        for (int ii = 0; ii < 4; ++ii) {
            int r = row0 + ty*4 + ii;
            float4 v = make_float4(acc[ii][0], acc[ii][1], acc[ii][2], acc[ii][3]);
            ((float4*)(outp + (size_t)r*HK + col0))[tx] = v;
        }
    }
}

// ---------------- Kernel 2: cooperative-unit MFMA attn ----------------
// one block per (b,i); 4 waves; all waves work the same (v,h) unit, split by nb.
__global__ __launch_bounds__(256, 2) void attn_kernel(
    const float* __restrict__ e, const float* __restrict__ k_RW,
    const float* __restrict__ mask, const int* __restrict__ adj,
    const float* __restrict__ ws, float* __restrict__ out)
{
    __shared__ unsigned short kb_s[2][NN*KPAD];  // 36864 B: K tile [j][k] dbuf
    __shared__ unsigned short wb_s[2][4096];     // 16384 B: W frags dbuf
    __shared__ float sc_s[HH*NN];                // 4096 B: selected scores
    __shared__ float kwm_s[NN];
    __shared__ int   ad_s[NN];

    const int t    = threadIdx.x;
    const int blk  = blockIdx.x;
    const int b    = blk >> 7;
    const int i    = blk & 127;
    const int lane = t & 63;
    const int w    = t >> 6;
    const int jl   = lane & 15;
    const int kq   = (lane >> 4) * 4;

    const unsigned short* Kbase = (const unsigned short*)(ws + 2*(size_t)MATSZ);
    const unsigned short* Vbf   = Kbase + 2*(size_t)MATSZ;
    const unsigned short* Wfg   = Kbase + 3*(size_t)MATSZ;

    // ---- phase 0: e-fragments straight into registers (no LDS round-trip) ----
    sh8 eF[2][2];
    const float* ep = e + (size_t)blk * (NN*CC);
    #pragma unroll
    for (int np = 0; np < 2; ++np) {
        const int nb = np*4 + w;
        const int j  = nb*16 + jl;
        #pragma unroll
        for (int cb = 0; cb < 2; ++cb) {
            const int c0 = cb*32 + ((lane>>4)&3)*8;
            float a0[4], a1[4];
            *(float4*)a0 = *(const float4*)(ep + j*CC + c0);
            *(float4*)a1 = *(const float4*)(ep + j*CC + c0 + 4);
            sh8 f;
            f[0]=(short)f2bf(a0[0]); f[1]=(short)f2bf(a0[1]);
            f[2]=(short)f2bf(a0[2]); f[3]=(short)f2bf(a0[3]);
            f[4]=(short)f2bf(a1[0]); f[5]=(short)f2bf(a1[1]);
            f[6]=(short)f2bf(a1[2]); f[7]=(short)f2bf(a1[3]);
            eF[np][cb] = f;
        }
    }
    if (t < NN) {
        kwm_s[t] = k_RW[(size_t)blk*NN + t] * mask[b*NN + t];
        ad_s[t]  = adj[(size_t)blk*NN + t];
    }
    const float maski = mask[b*NN + i];

    // ---- unit loop: stage (dbuf) + compute; prefetch next unit during compute ----
    // K tile per unit: 128 rows x 64 ushorts = 8192 ushorts; 256 threads x 32 ushorts
    // (4 x int4) each: thread -> row sj = t>>1, half sh = t&1, ushorts [sh*32, sh*32+32).
    const int sj = t >> 1;
    const int sh = t & 1;
    int4 kr0, kr1, kr2, kr3, wr0, wr1;
    {
        const unsigned short* ks = Kbase + (size_t)b*(NN*HK) + (size_t)sj*HK + sh*32;
        kr0 = ((const int4*)ks)[0]; kr1 = ((const int4*)ks)[1];
        kr2 = ((const int4*)ks)[2]; kr3 = ((const int4*)ks)[3];
        const unsigned short* wsc = Wfg + (size_t)t*16;
        wr0 = ((const int4*)wsc)[0]; wr1 = ((const int4*)wsc)[1];
    }

    #pragma unroll 1
    for (int unit = 0; unit < 16; ++unit) {
        const int buf = unit & 1;
        const int v   = unit >> 3;
        const int hh  = unit & 7;
        {   // commit staged registers to LDS
            unsigned short* kd = &kb_s[buf][sj*KPAD + sh*32];
            ((int4*)kd)[0] = kr0; ((int4*)kd)[1] = kr1;
            ((int4*)kd)[2] = kr2; ((int4*)kd)[3] = kr3;
            unsigned short* wd = &wb_s[buf][t*16];
            ((int4*)wd)[0] = wr0; ((int4*)wd)[1] = wr1;
        }
        __syncthreads();
        if (unit + 1 < 16) {   // prefetch next unit (latency hidden under compute)
            const int v2 = (unit+1) >> 3, h2 = (unit+1) & 7;
            const unsigned short* ks = Kbase + (size_t)v2*MATSZ + (size_t)b*(NN*HK)
                                     + (size_t)sj*HK + h2*KK + sh*32;
            kr0 = ((const int4*)ks)[0]; kr1 = ((const int4*)ks)[1];
            kr2 = ((const int4*)ks)[2]; kr3 = ((const int4*)ks)[3];
            const unsigned short* wsc = Wfg + (size_t)v2*32768 + (size_t)h2*4096 + (size_t)t*16;
            wr0 = ((const int4*)wsc)[0]; wr1 = ((const int4*)wsc)[1];
        }

        const float* Qrow = ws + (size_t)v*MATSZ + (size_t)blk*HK + hh*KK;
        float q4[4][4];
        #pragma unroll
        for (int mb = 0; mb < 4; ++mb)
            *(float4*)q4[mb] = *(const float4*)(Qrow + mb*16 + kq);
        sh8 aF[4][2];
        #pragma unroll
        for (int mb = 0; mb < 4; ++mb)
            #pragma unroll
            for (int cb = 0; cb < 2; ++cb)
                aF[mb][cb] = ((const sh8*)wb_s[buf])[(mb*2+cb)*64 + lane];
        const bool av = (v == 0);

        #pragma unroll
        for (int np = 0; np < 2; ++np) {
            const int nb = np*4 + w;
            const int j  = nb*16 + jl;
            f32x4 acc[4];
            #pragma unroll
            for (int mb = 0; mb < 4; ++mb) acc[mb] = (f32x4){0.f,0.f,0.f,0.f};
            #pragma unroll
            for (int cb = 0; cb < 2; ++cb) {
                sh8 bF = eF[np][cb];
                #pragma unroll
                for (int mb = 0; mb < 4; ++mb)
                    acc[mb] = __builtin_amdgcn_mfma_f32_16x16x32_bf16(
                                  aF[mb][cb], bF, acc[mb], 0, 0, 0);
            }
            const unsigned short* kr = &kb_s[buf][j*KPAD + kq];
            float p = 0.f;
            #pragma unroll
            for (int mb = 0; mb < 4; ++mb) {
                ushort4 kv = *(const ushort4*)(kr + mb*16);
                p += acc[mb][0] * (q4[mb][0] * bf2f(kv.x));
                p += acc[mb][1] * (q4[mb][1] * bf2f(kv.y));
                p += acc[mb][2] * (q4[mb][2] * bf2f(kv.z));
                p += acc[mb][3] * (q4[mb][3] * bf2f(kv.w));
            }
            p += __shfl_xor(p, 16);
            p += __shfl_xor(p, 32);
            if (lane < 16 && ((ad_s[j] != 0) == av)) sc_s[hh*NN + j] = p;
        }
        // next iteration's __syncthreads (after its LDS store to the other buffer)
        // guarantees compute(u) finished before buffer reuse at u+2.
    }
    __syncthreads();

    // ---- phase 2: exp * mask_i * mask_j * k_RW (global max cancels in ratio) ----
    #pragma unroll
    for (int r = 0; r < 4; ++r) {
        int idx = t + 256*r;
        int j = idx & 127;
        sc_s[idx] = __expf(sc_s[idx]) * kwm_s[j] * maski;
    }
    __syncthreads();

    // ---- phase 3: per-head denom + weighted V sum (V in bf16) ----
    const unsigned short* VB = Vbf + (size_t)b*(NN*HK);
    for (int hp = 0; hp < 2; ++hp) {
        const int hh = w + hp*4;
        float d = sc_s[hh*NN + lane] + sc_s[hh*NN + 64 + lane];
        #pragma unroll
        for (int mm = 32; mm >= 1; mm >>= 1) d += __shfl_xor(d, mm);
        float accv = 0.f;
        const unsigned short* vb = VB + hh*KK + lane;
        #pragma unroll 4
        for (int j4 = 0; j4 < 32; ++j4) {
            float wa[4];
            *(float4*)wa = ((float4*)sc_s)[hh*32 + j4];
            accv += wa[0] * bf2f(vb[(size_t)(j4*4+0)*HK]);
            accv += wa[1] * bf2f(vb[(size_t)(j4*4+1)*HK]);
            accv += wa[2] * bf2f(vb[(size_t)(j4*4+2)*HK]);
            accv += wa[3] * bf2f(vb[(size_t)(j4*4+3)*HK]);
        }
        out[(size_t)blk*HK + hh*KK + lane] = accv / fmaxf(d, 1e-6f);
    }
}

extern "C" void kernel_launch(void* const* d_in, const int* in_sizes, int n_in,
                              void* d_out, int out_size, void* d_ws, size_t ws_size,
                              hipStream_t stream) {
    const float* h    = (const float*)d_in[0];
    const float* e    = (const float*)d_in[1];
    const float* kRW  = (const float*)d_in[2];
    const float* mask = (const float*)d_in[3];
    const int*   adj  = (const int*)d_in[4];
    const float* Wq   = (const float*)d_in[5];
    const float* Wk   = (const float*)d_in[6];
    const float* Wv   = (const float*)d_in[7];
    const float* We   = (const float*)d_in[8];
    const float* Wq2  = (const float*)d_in[9];
    const float* Wk2  = (const float*)d_in[10];
    const float* We2  = (const float*)d_in[11];
    float* out = (float*)d_out;
    float* ws  = (float*)d_ws;   // 2*2MB f32 + 3*1MB bf16 + 128KB Wfrag ~= 7.1MB

    proj_kernel<<<dim3(16, 42), 256, 0, stream>>>(h, Wq, Wk, Wv, Wq2, Wk2, We, We2, ws);
    attn_kernel<<<dim3(1024), 256, 0, stream>>>(e, kRW, mask, adj, ws, out);
}